// Round 4
// baseline (583.592 us; speedup 1.0000x reference)
//
#include <hip/hip_runtime.h>
#include <math.h>

#pragma clang fp contract(off)

#define NN 2
#define VV 2048
#define FF 2048
#define HH 384
#define WW 384
#define TH 1024
#define TW 1024
#define EPSD 1e-08

// Separately-rounded fp32 multiply (blocks backend FMA fusion).
__device__ __forceinline__ float mulr(float a, float b) {
    float p = a * b;
    asm("" : "+v"(p));
    return p;
}

// Face record: 16 floats (all fp32 — vertex-level quantities stay fp32)
// [0]x0 [1]y0 [2]x1 [3]y1 [4]x2 [5]y2
// [6]ex0=x2-x1 [7]ey0=y2-y1 [8]ex1=x0-x2 [9]ey1=y0-y2 [10]ex2=x1-x0 [11]ey2=y1-y0
// [12]inv (fp32; NaN if !ok) [13]z0 [14]z1 [15]z2

__global__ __launch_bounds__(256) void setup_faces(
    const float* __restrict__ v, const float* __restrict__ campos,
    const float* __restrict__ camrot, const float* __restrict__ focal,
    const float* __restrict__ princpt, const int* __restrict__ vi,
    float* __restrict__ face, float4* __restrict__ bbox)
{
#pragma clang fp contract(off)
    int t = blockIdx.x * blockDim.x + threadIdx.x;
    if (t >= NN * FF) return;
    int n = t / FF, f = t % FF;
    const float* cr = camrot + n * 9;
    const float* cp = campos + n * 3;
    const float* fo = focal + n * 4;
    const float* pp = princpt + n * 2;
    float X[3], Y[3], Z[3];
    for (int k = 0; k < 3; ++k) {
        int vid = vi[f * 3 + k];
        const float* vp = v + ((size_t)n * VV + vid) * 3;
        float d0 = vp[0] - cp[0];
        float d1 = vp[1] - cp[1];
        float d2 = vp[2] - cp[2];
        float c0 = (mulr(cr[0], d0) + mulr(cr[1], d1)) + mulr(cr[2], d2);
        float c1 = (mulr(cr[3], d0) + mulr(cr[4], d1)) + mulr(cr[5], d2);
        float c2 = (mulr(cr[6], d0) + mulr(cr[7], d1)) + mulr(cr[8], d2);
        float u = c0 / c2;
        float w = c1 / c2;
        X[k] = (mulr(fo[0], u) + mulr(fo[1], w)) + pp[0];
        Y[k] = (mulr(fo[2], u) + mulr(fo[3], w)) + pp[1];
        Z[k] = c2;
    }
    // area/inv in fp32 (vertex-only math — matches ref's fp32 _bary area path)
    float area = mulr(X[1] - X[0], Y[2] - Y[0]) - mulr(Y[1] - Y[0], X[2] - X[0]);
    bool ok = fabsf(area) > 1e-9f;
    float inv = ok ? (1.0f / area) : __builtin_nanf("");
    float* fd = face + (size_t)t * 16;
    fd[0] = X[0]; fd[1] = Y[0]; fd[2] = X[1]; fd[3] = Y[1]; fd[4] = X[2]; fd[5] = Y[2];
    fd[6] = X[2] - X[1]; fd[7] = Y[2] - Y[1];
    fd[8] = X[0] - X[2]; fd[9] = Y[0] - Y[2];
    fd[10] = X[1] - X[0]; fd[11] = Y[1] - Y[0];
    fd[12] = inv;
    fd[13] = Z[0]; fd[14] = Z[1]; fd[15] = Z[2];
    float xmn = fminf(fminf(X[0], X[1]), X[2]);
    float xmx = fmaxf(fmaxf(X[0], X[1]), X[2]);
    float ymn = fminf(fminf(Y[0], Y[1]), Y[2]);
    float ymx = fmaxf(fmaxf(Y[0], Y[1]), Y[2]);
    bbox[t] = make_float4(xmn, ymn, xmx, ymx);
}

// Per-pixel barycentric evaluation in DOUBLE precision (fp32 vertex data,
// f64 pixel coords) — decisions become exact-real-arithmetic on the fp32
// vertex data, immune to fp32 edge-tie ambiguity.
__device__ __forceinline__ void bary3_f64(
    const float4 q0, const float4 q1, const float4 q2, const float4 q3,
    double px, double py, double& b0, double& b1, double& b2)
{
    double invd = (double)q3.x;
    b0 = ((double)q1.z * (py - (double)q0.w) - (double)q1.w * (px - (double)q0.z)) * invd;
    b1 = ((double)q2.x * (py - (double)q1.y) - (double)q2.y * (px - (double)q1.x)) * invd;
    b2 = ((double)q2.z * (py - (double)q0.y) - (double)q2.w * (px - (double)q0.x)) * invd;
}

__global__ __launch_bounds__(256) void raster(
    const float* __restrict__ face, const float4* __restrict__ bbox,
    int* __restrict__ ibuf)
{
    __shared__ int s_cnt;
    __shared__ int s_list[FF];
    int n = blockIdx.z;
    int tx0 = blockIdx.x * 16, ty0 = blockIdx.y * 16;
    int tid = threadIdx.x;
    if (tid == 0) s_cnt = 0;
    __syncthreads();
    float xlo = (float)tx0, xhi = (float)(tx0 + 16);
    float ylo = (float)ty0, yhi = (float)(ty0 + 16);
    for (int f = tid; f < FF; f += 256) {
        float4 bb = bbox[n * FF + f];
        if (bb.x <= xhi && bb.z >= xlo && bb.y <= yhi && bb.w >= ylo) {
            int p = atomicAdd(&s_cnt, 1);
            s_list[p] = f;
        }
    }
    __syncthreads();
    int cnt = s_cnt;
    double px = (double)(tx0 + (tid & 15)) + 0.5;
    double py = (double)(ty0 + (tid >> 4)) + 0.5;
    double best_d = INFINITY;
    int bf = -1;
    for (int i = 0; i < cnt; ++i) {
        int fid = __builtin_amdgcn_readfirstlane(s_list[i]);
        const float4* fp = (const float4*)(face + ((size_t)n * FF + fid) * 16);
        float4 q0 = fp[0];  // x0 y0 x1 y1
        float4 q1 = fp[1];  // x2 y2 ex0 ey0
        float4 q2 = fp[2];  // ex1 ey1 ex2 ey2
        float4 q3 = fp[3];  // inv z0 z1 z2
        double b0, b1, b2;
        bary3_f64(q0, q1, q2, q3, px, py, b0, b1, b2);
        bool inside = (b0 >= 0.0) && (b1 >= 0.0) && (b2 >= 0.0);
        if (!inside) continue;
        double zinv = (b0 / (double)q3.y + b1 / (double)q3.z) + b2 / (double)q3.w;
        if (zinv > EPSD) {
            double d = 1.0 / zinv;
            if (d < best_d || (d == best_d && fid < bf)) {
                best_d = d;
                bf = fid;
            }
        }
    }
    int x = tx0 + (tid & 15), y = ty0 + (tid >> 4);
    ibuf[((size_t)n * HH + y) * WW + x] = bf;
}

__global__ __launch_bounds__(256) void render(
    const float* __restrict__ face, const int* __restrict__ ibuf,
    const float* __restrict__ tex, const float* __restrict__ vt,
    const int* __restrict__ vti, float* __restrict__ out)
{
    int t = blockIdx.x * blockDim.x + threadIdx.x;
    if (t >= NN * HH * WW) return;
    int n = t / (HH * WW);
    int p = t % (HH * WW);
    int y = p / WW, x = p % WW;
    int f = ibuf[t];
    size_t o0 = ((size_t)(n * 3 + 0) * HH + y) * WW + x;
    size_t o1 = ((size_t)(n * 3 + 1) * HH + y) * WW + x;
    size_t o2 = ((size_t)(n * 3 + 2) * HH + y) * WW + x;
    if (f < 0) {
        out[o0] = 0.0f; out[o1] = 0.0f; out[o2] = 0.0f;
        return;
    }
    const float4* fp = (const float4*)(face + ((size_t)n * FF + f) * 16);
    float4 q0 = fp[0], q1 = fp[1], q2 = fp[2], q3 = fp[3];
    double px = (double)x + 0.5, py = (double)y + 0.5;
    double b0, b1, b2;
    bary3_f64(q0, q1, q2, q3, px, py, b0, b1, b2);
    double w0 = b0 / (double)q3.y;
    double w1 = b1 / (double)q3.z;
    double w2 = b2 / (double)q3.w;
    double s = (w0 + w1) + w2;
    double zq = fmax(s, EPSD);
    double bar0 = w0 / zq, bar1 = w1 / zq, bar2 = w2 / zq;
    int i0 = vti[f * 3 + 0], i1 = vti[f * 3 + 1], i2 = vti[f * 3 + 2];
    // uv = 2*vt - 1 computed in fp32 (vertex-level, matches ref), then f64
    double u0 = (double)(2.0f * vt[i0 * 2 + 0] - 1.0f), v0 = (double)(2.0f * vt[i0 * 2 + 1] - 1.0f);
    double u1 = (double)(2.0f * vt[i1 * 2 + 0] - 1.0f), v1 = (double)(2.0f * vt[i1 * 2 + 1] - 1.0f);
    double u2 = (double)(2.0f * vt[i2 * 2 + 0] - 1.0f), v2 = (double)(2.0f * vt[i2 * 2 + 1] - 1.0f);
    double gx = (u0 * bar0 + u1 * bar1) + u2 * bar2;
    double gy = (v0 * bar0 + v1 * bar1) + v2 * bar2;
    double ix = ((gx + 1.0) * (double)TW - 1.0) * 0.5;
    double iy = ((gy + 1.0) * (double)TH - 1.0) * 0.5;
    double fx0 = floor(ix), fy0 = floor(iy);
    double wx = ix - fx0, wy = iy - fy0;
    int x0 = min(max((int)fx0, 0), TW - 1);
    int x1 = min(max((int)fx0 + 1, 0), TW - 1);
    int y0 = min(max((int)fy0, 0), TH - 1);
    int y1 = min(max((int)fy0 + 1, 0), TH - 1);
    double omwx = 1.0 - wx, omwy = 1.0 - wy;
    #pragma unroll
    for (int c = 0; c < 3; ++c) {
        const float* tc = tex + ((size_t)n * 3 + c) * TH * TW;
        double g00 = (double)tc[(size_t)y0 * TW + x0];
        double g01 = (double)tc[(size_t)y0 * TW + x1];
        double g10 = (double)tc[(size_t)y1 * TW + x0];
        double g11 = (double)tc[(size_t)y1 * TW + x1];
        double val = (((g00 * omwx) * omwy + (g01 * wx) * omwy)
                      + (g10 * omwx) * wy) + (g11 * wx) * wy;
        size_t oo = (c == 0) ? o0 : ((c == 1) ? o1 : o2);
        out[oo] = (float)val;
    }
}

extern "C" void kernel_launch(void* const* d_in, const int* in_sizes, int n_in,
                              void* d_out, int out_size, void* d_ws, size_t ws_size,
                              hipStream_t stream) {
    const float* v = (const float*)d_in[0];
    const float* tex = (const float*)d_in[1];
    const float* campos = (const float*)d_in[2];
    const float* camrot = (const float*)d_in[3];
    const float* focal = (const float*)d_in[4];
    const float* princpt = (const float*)d_in[5];
    const float* vt = (const float*)d_in[6];
    const int* vi = (const int*)d_in[7];
    const int* vti = (const int*)d_in[8];
    float* out = (float*)d_out;

    char* ws = (char*)d_ws;
    float* face = (float*)ws;                                 // NN*FF*16*4 = 262144 B
    float4* bbox = (float4*)(ws + (size_t)NN * FF * 16 * 4);  // +65536 B
    int* ibuf = (int*)(ws + (size_t)NN * FF * 16 * 4 + (size_t)NN * FF * 16);

    setup_faces<<<dim3((NN * FF + 255) / 256), dim3(256), 0, stream>>>(
        v, campos, camrot, focal, princpt, vi, face, bbox);
    raster<<<dim3(WW / 16, HH / 16, NN), dim3(256), 0, stream>>>(face, bbox, ibuf);
    render<<<dim3((NN * HH * WW + 255) / 256), dim3(256), 0, stream>>>(
        face, ibuf, tex, vt, vti, out);
}

// Round 5
// 225.475 us; speedup vs baseline: 2.5883x; 2.5883x over previous
//
#include <hip/hip_runtime.h>
#include <math.h>

#pragma clang fp contract(off)

#define NN 2
#define VV 2048
#define FF 2048
#define HH 384
#define WW 384
#define TH 1024
#define TW 1024
#define EPSD 1e-08

// Separately-rounded fp32 multiply (blocks backend FMA fusion).
__device__ __forceinline__ float mulr(float a, float b) {
    float p = a * b;
    asm("" : "+v"(p));
    return p;
}

// fp32 face record (render path — identical to round 4):
// [0]x0 [1]y0 [2]x1 [3]y1 [4]x2 [5]y2
// [6]ex0 [7]ey0 [8]ex1 [9]ey1 [10]ex2 [11]ey2 [12]inv(NaN if !ok) [13]z0 [14]z1 [15]z2
//
// f64 face record (raster fast path) — f64 casts of the SAME f32 values so the
// decision set matches round 4 to <=1ulp-f64:
// [0]x0 [1]y0 [2]x1 [3]y1 [4]x2 [5]y2
// [6]ex0 [7]ey0 [8]ex1 [9]ey1 [10]ex2 [11]ey2 [12]inv [13]1/z0 [14]1/z1 [15]1/z2

__global__ __launch_bounds__(256) void setup_faces(
    const float* __restrict__ v, const float* __restrict__ campos,
    const float* __restrict__ camrot, const float* __restrict__ focal,
    const float* __restrict__ princpt, const int* __restrict__ vi,
    float* __restrict__ face, double* __restrict__ dface, float4* __restrict__ bbox)
{
#pragma clang fp contract(off)
    int t = blockIdx.x * blockDim.x + threadIdx.x;
    if (t >= NN * FF) return;
    int n = t / FF, f = t % FF;
    const float* cr = camrot + n * 9;
    const float* cp = campos + n * 3;
    const float* fo = focal + n * 4;
    const float* pp = princpt + n * 2;
    float X[3], Y[3], Z[3];
    for (int k = 0; k < 3; ++k) {
        int vid = vi[f * 3 + k];
        const float* vp = v + ((size_t)n * VV + vid) * 3;
        float d0 = vp[0] - cp[0];
        float d1 = vp[1] - cp[1];
        float d2 = vp[2] - cp[2];
        float c0 = (mulr(cr[0], d0) + mulr(cr[1], d1)) + mulr(cr[2], d2);
        float c1 = (mulr(cr[3], d0) + mulr(cr[4], d1)) + mulr(cr[5], d2);
        float c2 = (mulr(cr[6], d0) + mulr(cr[7], d1)) + mulr(cr[8], d2);
        float u = c0 / c2;
        float w = c1 / c2;
        X[k] = (mulr(fo[0], u) + mulr(fo[1], w)) + pp[0];
        Y[k] = (mulr(fo[2], u) + mulr(fo[3], w)) + pp[1];
        Z[k] = c2;
    }
    float area = mulr(X[1] - X[0], Y[2] - Y[0]) - mulr(Y[1] - Y[0], X[2] - X[0]);
    bool ok = fabsf(area) > 1e-9f;
    float inv = ok ? (1.0f / area) : __builtin_nanf("");
    // f32 diffs computed exactly like round 4 (then cast) — keeps decisions stable
    float e0x = X[2] - X[1], e0y = Y[2] - Y[1];
    float e1x = X[0] - X[2], e1y = Y[0] - Y[2];
    float e2x = X[1] - X[0], e2y = Y[1] - Y[0];
    float* fd = face + (size_t)t * 16;
    fd[0] = X[0]; fd[1] = Y[0]; fd[2] = X[1]; fd[3] = Y[1]; fd[4] = X[2]; fd[5] = Y[2];
    fd[6] = e0x; fd[7] = e0y;
    fd[8] = e1x; fd[9] = e1y;
    fd[10] = e2x; fd[11] = e2y;
    fd[12] = inv;
    fd[13] = Z[0]; fd[14] = Z[1]; fd[15] = Z[2];
    double* dd = dface + (size_t)t * 16;
    dd[0] = (double)X[0]; dd[1] = (double)Y[0];
    dd[2] = (double)X[1]; dd[3] = (double)Y[1];
    dd[4] = (double)X[2]; dd[5] = (double)Y[2];
    dd[6] = (double)e0x; dd[7] = (double)e0y;
    dd[8] = (double)e1x; dd[9] = (double)e1y;
    dd[10] = (double)e2x; dd[11] = (double)e2y;
    dd[12] = (double)inv;
    dd[13] = 1.0 / (double)Z[0];
    dd[14] = 1.0 / (double)Z[1];
    dd[15] = 1.0 / (double)Z[2];
    float xmn = fminf(fminf(X[0], X[1]), X[2]);
    float xmx = fmaxf(fmaxf(X[0], X[1]), X[2]);
    float ymn = fminf(fminf(Y[0], Y[1]), Y[2]);
    float ymx = fmaxf(fmaxf(Y[0], Y[1]), Y[2]);
    bbox[t] = make_float4(xmn, ymn, xmx, ymx);
}

// 8x8 pixel tile per block; 256 threads = 4 waves; wave w handles candidates
// w, w+4, w+8, ... for all 64 pixels (lane = pixel); LDS merge at the end.
__global__ __launch_bounds__(256) void raster(
    const double* __restrict__ dface, const float4* __restrict__ bbox,
    int* __restrict__ ibuf)
{
#pragma clang fp contract(fast)
    __shared__ int s_cnt;
    __shared__ int s_list[FF];
    __shared__ double s_z[4 * 64];
    __shared__ int s_f[4 * 64];
    int n = blockIdx.z;
    int tx0 = blockIdx.x * 8, ty0 = blockIdx.y * 8;
    int tid = threadIdx.x;
    int lane = tid & 63;
    int wv = tid >> 6;
    if (tid == 0) s_cnt = 0;
    __syncthreads();
    float xlo = (float)tx0, xhi = (float)(tx0 + 8);
    float ylo = (float)ty0, yhi = (float)(ty0 + 8);
    for (int f = tid; f < FF; f += 256) {
        float4 bb = bbox[n * FF + f];
        if (bb.x <= xhi && bb.z >= xlo && bb.y <= yhi && bb.w >= ylo) {
            int p = atomicAdd(&s_cnt, 1);
            s_list[p] = f;
        }
    }
    __syncthreads();
    int cnt = s_cnt;
    double px = (double)(tx0 + (lane & 7)) + 0.5;
    double py = (double)(ty0 + (lane >> 3)) + 0.5;
    double best = 0.0;
    int bf = -1;
    for (int i = wv; i < cnt; i += 4) {
        int fid = __builtin_amdgcn_readfirstlane(s_list[i]);
        const double* fd = dface + ((size_t)n * FF + fid) * 16;
        double x0 = fd[0], y0 = fd[1], x1 = fd[2], y1 = fd[3], x2 = fd[4], y2 = fd[5];
        double e0x = fd[6], e0y = fd[7], e1x = fd[8], e1y = fd[9], e2x = fd[10], e2y = fd[11];
        double inv = fd[12], rz0 = fd[13], rz1 = fd[14], rz2 = fd[15];
        double b0 = (e0x * (py - y1) - e0y * (px - x1)) * inv;
        double b1 = (e1x * (py - y2) - e1y * (px - x2)) * inv;
        double b2 = (e2x * (py - y0) - e2y * (px - x0)) * inv;
        double zinv = b0 * rz0 + b1 * rz1 + b2 * rz2;
        if (b0 >= 0.0 && b1 >= 0.0 && b2 >= 0.0 && zinv > EPSD) {
            if (zinv > best || (zinv == best && fid < bf)) {
                best = zinv;
                bf = fid;
            }
        }
    }
    s_z[wv * 64 + lane] = best;
    s_f[wv * 64 + lane] = bf;
    __syncthreads();
    if (tid < 64) {
        for (int w = 1; w < 4; ++w) {
            double z = s_z[w * 64 + tid];
            int ff = s_f[w * 64 + tid];
            if (ff >= 0 && (bf < 0 || z > best || (z == best && ff < bf))) {
                best = z;
                bf = ff;
            }
        }
        int x = tx0 + (tid & 7), y = ty0 + (tid >> 3);
        ibuf[((size_t)n * HH + y) * WW + x] = bf;
    }
}

// render: UNCHANGED from round 4 (op-for-op) — continuous path stays bitwise identical.
__device__ __forceinline__ void bary3_f64(
    const float4 q0, const float4 q1, const float4 q2, const float4 q3,
    double px, double py, double& b0, double& b1, double& b2)
{
    double invd = (double)q3.x;
    b0 = ((double)q1.z * (py - (double)q0.w) - (double)q1.w * (px - (double)q0.z)) * invd;
    b1 = ((double)q2.x * (py - (double)q1.y) - (double)q2.y * (px - (double)q1.x)) * invd;
    b2 = ((double)q2.z * (py - (double)q0.y) - (double)q2.w * (px - (double)q0.x)) * invd;
}

__global__ __launch_bounds__(256) void render(
    const float* __restrict__ face, const int* __restrict__ ibuf,
    const float* __restrict__ tex, const float* __restrict__ vt,
    const int* __restrict__ vti, float* __restrict__ out)
{
    int t = blockIdx.x * blockDim.x + threadIdx.x;
    if (t >= NN * HH * WW) return;
    int n = t / (HH * WW);
    int p = t % (HH * WW);
    int y = p / WW, x = p % WW;
    int f = ibuf[t];
    size_t o0 = ((size_t)(n * 3 + 0) * HH + y) * WW + x;
    size_t o1 = ((size_t)(n * 3 + 1) * HH + y) * WW + x;
    size_t o2 = ((size_t)(n * 3 + 2) * HH + y) * WW + x;
    if (f < 0) {
        out[o0] = 0.0f; out[o1] = 0.0f; out[o2] = 0.0f;
        return;
    }
    const float4* fp = (const float4*)(face + ((size_t)n * FF + f) * 16);
    float4 q0 = fp[0], q1 = fp[1], q2 = fp[2], q3 = fp[3];
    double px = (double)x + 0.5, py = (double)y + 0.5;
    double b0, b1, b2;
    bary3_f64(q0, q1, q2, q3, px, py, b0, b1, b2);
    double w0 = b0 / (double)q3.y;
    double w1 = b1 / (double)q3.z;
    double w2 = b2 / (double)q3.w;
    double s = (w0 + w1) + w2;
    double zq = fmax(s, EPSD);
    double bar0 = w0 / zq, bar1 = w1 / zq, bar2 = w2 / zq;
    int i0 = vti[f * 3 + 0], i1 = vti[f * 3 + 1], i2 = vti[f * 3 + 2];
    double u0 = (double)(2.0f * vt[i0 * 2 + 0] - 1.0f), v0 = (double)(2.0f * vt[i0 * 2 + 1] - 1.0f);
    double u1 = (double)(2.0f * vt[i1 * 2 + 0] - 1.0f), v1 = (double)(2.0f * vt[i1 * 2 + 1] - 1.0f);
    double u2 = (double)(2.0f * vt[i2 * 2 + 0] - 1.0f), v2 = (double)(2.0f * vt[i2 * 2 + 1] - 1.0f);
    double gx = (u0 * bar0 + u1 * bar1) + u2 * bar2;
    double gy = (v0 * bar0 + v1 * bar1) + v2 * bar2;
    double ix = ((gx + 1.0) * (double)TW - 1.0) * 0.5;
    double iy = ((gy + 1.0) * (double)TH - 1.0) * 0.5;
    double fx0 = floor(ix), fy0 = floor(iy);
    double wx = ix - fx0, wy = iy - fy0;
    int x0 = min(max((int)fx0, 0), TW - 1);
    int x1 = min(max((int)fx0 + 1, 0), TW - 1);
    int y0 = min(max((int)fy0, 0), TH - 1);
    int y1 = min(max((int)fy0 + 1, 0), TH - 1);
    double omwx = 1.0 - wx, omwy = 1.0 - wy;
    #pragma unroll
    for (int c = 0; c < 3; ++c) {
        const float* tc = tex + ((size_t)n * 3 + c) * TH * TW;
        double g00 = (double)tc[(size_t)y0 * TW + x0];
        double g01 = (double)tc[(size_t)y0 * TW + x1];
        double g10 = (double)tc[(size_t)y1 * TW + x0];
        double g11 = (double)tc[(size_t)y1 * TW + x1];
        double val = (((g00 * omwx) * omwy + (g01 * wx) * omwy)
                      + (g10 * omwx) * wy) + (g11 * wx) * wy;
        size_t oo = (c == 0) ? o0 : ((c == 1) ? o1 : o2);
        out[oo] = (float)val;
    }
}

extern "C" void kernel_launch(void* const* d_in, const int* in_sizes, int n_in,
                              void* d_out, int out_size, void* d_ws, size_t ws_size,
                              hipStream_t stream) {
    const float* v = (const float*)d_in[0];
    const float* tex = (const float*)d_in[1];
    const float* campos = (const float*)d_in[2];
    const float* camrot = (const float*)d_in[3];
    const float* focal = (const float*)d_in[4];
    const float* princpt = (const float*)d_in[5];
    const float* vt = (const float*)d_in[6];
    const int* vi = (const int*)d_in[7];
    const int* vti = (const int*)d_in[8];
    float* out = (float*)d_out;

    char* ws = (char*)d_ws;
    float* face = (float*)ws;                                  // 262144 B
    float4* bbox = (float4*)(ws + 262144);                     // +65536 B
    double* dface = (double*)(ws + 262144 + 65536);            // +524288 B (8B aligned)
    int* ibuf = (int*)(ws + 262144 + 65536 + 524288);          // +294912*4 B

    setup_faces<<<dim3((NN * FF + 255) / 256), dim3(256), 0, stream>>>(
        v, campos, camrot, focal, princpt, vi, face, dface, bbox);
    raster<<<dim3(WW / 8, HH / 8, NN), dim3(256), 0, stream>>>(dface, bbox, ibuf);
    render<<<dim3((NN * HH * WW + 255) / 256), dim3(256), 0, stream>>>(
        face, ibuf, tex, vt, vti, out);
}

// Round 6
// 211.295 us; speedup vs baseline: 2.7620x; 1.0671x over previous
//
#include <hip/hip_runtime.h>
#include <math.h>

#pragma clang fp contract(off)

#define NN 2
#define VV 2048
#define FF 2048
#define HH 384
#define WW 384
#define TH 1024
#define TW 1024
#define EPSD 1e-08
#define CAP 256   // faces cached in LDS per tile

// Separately-rounded fp32 multiply (blocks backend FMA fusion).
__device__ __forceinline__ float mulr(float a, float b) {
    float p = a * b;
    asm("" : "+v"(p));
    return p;
}

// fp32 face record (render path — identical to rounds 4/5):
// [0]x0 [1]y0 [2]x1 [3]y1 [4]x2 [5]y2
// [6]ex0 [7]ey0 [8]ex1 [9]ey1 [10]ex2 [11]ey2 [12]inv(NaN if !ok) [13]z0 [14]z1 [15]z2
//
// f64 face record (raster eval — identical values to round 5):
// [0..5] verts, [6..11] edges, [12] inv, [13..15] 1/z
//
// cull record (float4 x4 per face):
// [0] bbox (xmn,ymn,xmx,ymx)
// [1] (A0s,B0s,C0s,A1s)  [2] (B1s,C1s,A2s,B2s)  [3] (C2s,0,0,0)
// where raw_i = A_i*px + B_i*py + C_i is the UNSCALED edge function and the
// s-suffix means multiplied by sign(area); inside requires raw_i*s >= 0.
// !ok faces get C's = -3e30 so every tile test rejects them.

__global__ __launch_bounds__(256) void setup_faces(
    const float* __restrict__ v, const float* __restrict__ campos,
    const float* __restrict__ camrot, const float* __restrict__ focal,
    const float* __restrict__ princpt, const int* __restrict__ vi,
    float* __restrict__ face, double* __restrict__ dface, float4* __restrict__ cull)
{
#pragma clang fp contract(off)
    int t = blockIdx.x * blockDim.x + threadIdx.x;
    if (t >= NN * FF) return;
    int n = t / FF, f = t % FF;
    const float* cr = camrot + n * 9;
    const float* cp = campos + n * 3;
    const float* fo = focal + n * 4;
    const float* pp = princpt + n * 2;
    float X[3], Y[3], Z[3];
    for (int k = 0; k < 3; ++k) {
        int vid = vi[f * 3 + k];
        const float* vp = v + ((size_t)n * VV + vid) * 3;
        float d0 = vp[0] - cp[0];
        float d1 = vp[1] - cp[1];
        float d2 = vp[2] - cp[2];
        float c0 = (mulr(cr[0], d0) + mulr(cr[1], d1)) + mulr(cr[2], d2);
        float c1 = (mulr(cr[3], d0) + mulr(cr[4], d1)) + mulr(cr[5], d2);
        float c2 = (mulr(cr[6], d0) + mulr(cr[7], d1)) + mulr(cr[8], d2);
        float u = c0 / c2;
        float w = c1 / c2;
        X[k] = (mulr(fo[0], u) + mulr(fo[1], w)) + pp[0];
        Y[k] = (mulr(fo[2], u) + mulr(fo[3], w)) + pp[1];
        Z[k] = c2;
    }
    float area = mulr(X[1] - X[0], Y[2] - Y[0]) - mulr(Y[1] - Y[0], X[2] - X[0]);
    bool ok = fabsf(area) > 1e-9f;
    float inv = ok ? (1.0f / area) : __builtin_nanf("");
    float e0x = X[2] - X[1], e0y = Y[2] - Y[1];
    float e1x = X[0] - X[2], e1y = Y[0] - Y[2];
    float e2x = X[1] - X[0], e2y = Y[1] - Y[0];
    float* fd = face + (size_t)t * 16;
    fd[0] = X[0]; fd[1] = Y[0]; fd[2] = X[1]; fd[3] = Y[1]; fd[4] = X[2]; fd[5] = Y[2];
    fd[6] = e0x; fd[7] = e0y;
    fd[8] = e1x; fd[9] = e1y;
    fd[10] = e2x; fd[11] = e2y;
    fd[12] = inv;
    fd[13] = Z[0]; fd[14] = Z[1]; fd[15] = Z[2];
    double* dd = dface + (size_t)t * 16;
    dd[0] = (double)X[0]; dd[1] = (double)Y[0];
    dd[2] = (double)X[1]; dd[3] = (double)Y[1];
    dd[4] = (double)X[2]; dd[5] = (double)Y[2];
    dd[6] = (double)e0x; dd[7] = (double)e0y;
    dd[8] = (double)e1x; dd[9] = (double)e1y;
    dd[10] = (double)e2x; dd[11] = (double)e2y;
    dd[12] = (double)inv;
    dd[13] = 1.0 / (double)Z[0];
    dd[14] = 1.0 / (double)Z[1];
    dd[15] = 1.0 / (double)Z[2];
    // cull record
    float s = (area > 0.0f) ? 1.0f : -1.0f;
    float A0 = -e0y * s, B0 = e0x * s;
    float C0 = s * (float)((double)e0y * (double)X[1] - (double)e0x * (double)Y[1]);
    float A1 = -e1y * s, B1 = e1x * s;
    float C1 = s * (float)((double)e1y * (double)X[2] - (double)e1x * (double)Y[2]);
    float A2 = -e2y * s, B2 = e2x * s;
    float C2 = s * (float)((double)e2y * (double)X[0] - (double)e2x * (double)Y[0]);
    if (!ok) { C0 = -3e30f; C1 = -3e30f; C2 = -3e30f; }
    float xmn = fminf(fminf(X[0], X[1]), X[2]);
    float xmx = fmaxf(fmaxf(X[0], X[1]), X[2]);
    float ymn = fminf(fminf(Y[0], Y[1]), Y[2]);
    float ymx = fmaxf(fmaxf(Y[0], Y[1]), Y[2]);
    float4* cu = cull + (size_t)t * 4;
    cu[0] = make_float4(xmn, ymn, xmx, ymx);
    cu[1] = make_float4(A0, B0, C0, A1);
    cu[2] = make_float4(B1, C1, A2, B2);
    cu[3] = make_float4(C2, 0.0f, 0.0f, 0.0f);
}

__device__ __forceinline__ bool edge_keep(float A, float B, float C,
                                          float xlo, float xhi, float ylo, float yhi) {
    // conservative: keep unless the whole tile is strictly outside this edge
    float m = A * ((A > 0.0f) ? xhi : xlo) + B * ((B > 0.0f) ? yhi : ylo) + C;
    return m >= -1.0f;   // margin 1.0 raw-units ~ 0.01 px; f32 error << margin
}

struct FD { double v[16]; };

// f64 eval — character-identical arithmetic to round 5 (proven decision set)
__device__ __forceinline__ void upd_face(const FD& fd, double px, double py,
                                         int fid, double& best, int& bf) {
#pragma clang fp contract(fast)
    double x0 = fd.v[0], y0 = fd.v[1], x1 = fd.v[2], y1 = fd.v[3], x2 = fd.v[4], y2 = fd.v[5];
    double e0x = fd.v[6], e0y = fd.v[7], e1x = fd.v[8], e1y = fd.v[9], e2x = fd.v[10], e2y = fd.v[11];
    double inv = fd.v[12], rz0 = fd.v[13], rz1 = fd.v[14], rz2 = fd.v[15];
    double b0 = (e0x * (py - y1) - e0y * (px - x1)) * inv;
    double b1 = (e1x * (py - y2) - e1y * (px - x2)) * inv;
    double b2 = (e2x * (py - y0) - e2y * (px - x0)) * inv;
    double zinv = b0 * rz0 + b1 * rz1 + b2 * rz2;
    if (b0 >= 0.0 && b1 >= 0.0 && b2 >= 0.0 && zinv > EPSD) {
        if (zinv > best || (zinv == best && fid < bf)) {
            best = zinv;
            bf = fid;
        }
    }
}

// 8x8 pixel tile; 256 threads = 4 waves; wave w takes candidates w, w+4, ...
__global__ __launch_bounds__(256) void raster(
    const double* __restrict__ dface, const float4* __restrict__ cull,
    int* __restrict__ ibuf)
{
#pragma clang fp contract(fast)
    __shared__ int s_cnt;
    __shared__ int s_list[FF];
    __shared__ double s_face[CAP * 16];
    __shared__ double s_z[4 * 64];
    __shared__ int s_f[4 * 64];
    int n = blockIdx.z;
    int tx0 = blockIdx.x * 8, ty0 = blockIdx.y * 8;
    int tid = threadIdx.x;
    int lane = tid & 63;
    int wv = tid >> 6;
    if (tid == 0) s_cnt = 0;
    __syncthreads();
    float xlo = (float)tx0, xhi = (float)(tx0 + 8);
    float ylo = (float)ty0, yhi = (float)(ty0 + 8);
    for (int f = tid; f < FF; f += 256) {
        const float4* cu = cull + ((size_t)n * FF + f) * 4;
        float4 bb = cu[0];
        if (bb.x <= xhi && bb.z >= xlo && bb.y <= yhi && bb.w >= ylo) {
            float4 c1 = cu[1], c2 = cu[2], c3 = cu[3];
            if (edge_keep(c1.x, c1.y, c1.z, xlo, xhi, ylo, yhi) &&
                edge_keep(c1.w, c2.x, c2.y, xlo, xhi, ylo, yhi) &&
                edge_keep(c2.z, c2.w, c3.x, xlo, xhi, ylo, yhi)) {
                int p = atomicAdd(&s_cnt, 1);
                s_list[p] = f;
            }
        }
    }
    __syncthreads();
    int cnt = s_cnt;
    // stage first CAP face records into LDS (coalesced 128B copies)
    int ncache = (cnt < CAP) ? cnt : CAP;
    for (int idx = tid; idx < ncache * 16; idx += 256) {
        int pos = idx >> 4;
        int wrd = idx & 15;
        s_face[idx] = dface[((size_t)n * FF + s_list[pos]) * 16 + wrd];
    }
    __syncthreads();
    double px = (double)(tx0 + (lane & 7)) + 0.5;
    double py = (double)(ty0 + (lane >> 3)) + 0.5;
    double best = 0.0;
    int bf = -1;
    int i = wv;
    for (; i < ncache; i += 4) {
        int fid = __builtin_amdgcn_readfirstlane(s_list[i]);
        FD fd = *(const FD*)(s_face + i * 16);
        upd_face(fd, px, py, fid, best, bf);
    }
    for (; i < cnt; i += 4) {   // rare overflow tail from global
        int fid = __builtin_amdgcn_readfirstlane(s_list[i]);
        FD fd = *(const FD*)(dface + ((size_t)n * FF + fid) * 16);
        upd_face(fd, px, py, fid, best, bf);
    }
    s_z[wv * 64 + lane] = best;
    s_f[wv * 64 + lane] = bf;
    __syncthreads();
    if (tid < 64) {
        for (int w = 1; w < 4; ++w) {
            double z = s_z[w * 64 + tid];
            int ff = s_f[w * 64 + tid];
            if (ff >= 0 && (bf < 0 || z > best || (z == best && ff < bf))) {
                best = z;
                bf = ff;
            }
        }
        int x = tx0 + (tid & 7), y = ty0 + (tid >> 3);
        ibuf[((size_t)n * HH + y) * WW + x] = bf;
    }
}

// render: UNCHANGED from rounds 4/5 (op-for-op).
__device__ __forceinline__ void bary3_f64(
    const float4 q0, const float4 q1, const float4 q2, const float4 q3,
    double px, double py, double& b0, double& b1, double& b2)
{
    double invd = (double)q3.x;
    b0 = ((double)q1.z * (py - (double)q0.w) - (double)q1.w * (px - (double)q0.z)) * invd;
    b1 = ((double)q2.x * (py - (double)q1.y) - (double)q2.y * (px - (double)q1.x)) * invd;
    b2 = ((double)q2.z * (py - (double)q0.y) - (double)q2.w * (px - (double)q0.x)) * invd;
}

__global__ __launch_bounds__(256) void render(
    const float* __restrict__ face, const int* __restrict__ ibuf,
    const float* __restrict__ tex, const float* __restrict__ vt,
    const int* __restrict__ vti, float* __restrict__ out)
{
    int t = blockIdx.x * blockDim.x + threadIdx.x;
    if (t >= NN * HH * WW) return;
    int n = t / (HH * WW);
    int p = t % (HH * WW);
    int y = p / WW, x = p % WW;
    int f = ibuf[t];
    size_t o0 = ((size_t)(n * 3 + 0) * HH + y) * WW + x;
    size_t o1 = ((size_t)(n * 3 + 1) * HH + y) * WW + x;
    size_t o2 = ((size_t)(n * 3 + 2) * HH + y) * WW + x;
    if (f < 0) {
        out[o0] = 0.0f; out[o1] = 0.0f; out[o2] = 0.0f;
        return;
    }
    const float4* fp = (const float4*)(face + ((size_t)n * FF + f) * 16);
    float4 q0 = fp[0], q1 = fp[1], q2 = fp[2], q3 = fp[3];
    double px = (double)x + 0.5, py = (double)y + 0.5;
    double b0, b1, b2;
    bary3_f64(q0, q1, q2, q3, px, py, b0, b1, b2);
    double w0 = b0 / (double)q3.y;
    double w1 = b1 / (double)q3.z;
    double w2 = b2 / (double)q3.w;
    double s = (w0 + w1) + w2;
    double zq = fmax(s, EPSD);
    double bar0 = w0 / zq, bar1 = w1 / zq, bar2 = w2 / zq;
    int i0 = vti[f * 3 + 0], i1 = vti[f * 3 + 1], i2 = vti[f * 3 + 2];
    double u0 = (double)(2.0f * vt[i0 * 2 + 0] - 1.0f), v0 = (double)(2.0f * vt[i0 * 2 + 1] - 1.0f);
    double u1 = (double)(2.0f * vt[i1 * 2 + 0] - 1.0f), v1 = (double)(2.0f * vt[i1 * 2 + 1] - 1.0f);
    double u2 = (double)(2.0f * vt[i2 * 2 + 0] - 1.0f), v2 = (double)(2.0f * vt[i2 * 2 + 1] - 1.0f);
    double gx = (u0 * bar0 + u1 * bar1) + u2 * bar2;
    double gy = (v0 * bar0 + v1 * bar1) + v2 * bar2;
    double ix = ((gx + 1.0) * (double)TW - 1.0) * 0.5;
    double iy = ((gy + 1.0) * (double)TH - 1.0) * 0.5;
    double fx0 = floor(ix), fy0 = floor(iy);
    double wx = ix - fx0, wy = iy - fy0;
    int x0 = min(max((int)fx0, 0), TW - 1);
    int x1 = min(max((int)fx0 + 1, 0), TW - 1);
    int y0 = min(max((int)fy0, 0), TH - 1);
    int y1 = min(max((int)fy0 + 1, 0), TH - 1);
    double omwx = 1.0 - wx, omwy = 1.0 - wy;
    #pragma unroll
    for (int c = 0; c < 3; ++c) {
        const float* tc = tex + ((size_t)n * 3 + c) * TH * TW;
        double g00 = (double)tc[(size_t)y0 * TW + x0];
        double g01 = (double)tc[(size_t)y0 * TW + x1];
        double g10 = (double)tc[(size_t)y1 * TW + x0];
        double g11 = (double)tc[(size_t)y1 * TW + x1];
        double val = (((g00 * omwx) * omwy + (g01 * wx) * omwy)
                      + (g10 * omwx) * wy) + (g11 * wx) * wy;
        size_t oo = (c == 0) ? o0 : ((c == 1) ? o1 : o2);
        out[oo] = (float)val;
    }
}

extern "C" void kernel_launch(void* const* d_in, const int* in_sizes, int n_in,
                              void* d_out, int out_size, void* d_ws, size_t ws_size,
                              hipStream_t stream) {
    const float* v = (const float*)d_in[0];
    const float* tex = (const float*)d_in[1];
    const float* campos = (const float*)d_in[2];
    const float* camrot = (const float*)d_in[3];
    const float* focal = (const float*)d_in[4];
    const float* princpt = (const float*)d_in[5];
    const float* vt = (const float*)d_in[6];
    const int* vi = (const int*)d_in[7];
    const int* vti = (const int*)d_in[8];
    float* out = (float*)d_out;

    char* ws = (char*)d_ws;
    double* dface = (double*)ws;                       // 524288 B (8B aligned first)
    float* face = (float*)(ws + 524288);               // +262144 B
    float4* cull = (float4*)(ws + 524288 + 262144);    // +262144 B
    int* ibuf = (int*)(ws + 524288 + 262144 + 262144); // +1179648 B

    setup_faces<<<dim3((NN * FF + 255) / 256), dim3(256), 0, stream>>>(
        v, campos, camrot, focal, princpt, vi, face, dface, cull);
    raster<<<dim3(WW / 8, HH / 8, NN), dim3(256), 0, stream>>>(dface, cull, ibuf);
    render<<<dim3((NN * HH * WW + 255) / 256), dim3(256), 0, stream>>>(
        face, ibuf, tex, vt, vti, out);
}

// Round 7
// 192.854 us; speedup vs baseline: 3.0261x; 1.0956x over previous
//
#include <hip/hip_runtime.h>
#include <math.h>

#pragma clang fp contract(off)

#define NN 2
#define VV 2048
#define FF 2048
#define HH 384
#define WW 384
#define TH 1024
#define TW 1024
#define EPSD 1e-08

// Separately-rounded fp32 multiply (blocks backend FMA fusion).
__device__ __forceinline__ float mulr(float a, float b) {
    float p = a * b;
    asm("" : "+v"(p));
    return p;
}

// fp32 face record (render path — identical to rounds 4/5/6):
// [0]x0 [1]y0 [2]x1 [3]y1 [4]x2 [5]y2
// [6]ex0 [7]ey0 [8]ex1 [9]ey1 [10]ex2 [11]ey2 [12]inv(NaN if !ok) [13]z0 [14]z1 [15]z2
//
// f64 affine record (raster eval), 16 doubles (12 used):
// b_i(px,py) = G[3i]*px + G[3i+1]*py + G[3i+2]   (i=0,1,2)
// zinv(px,py) = G[9]*px + G[10]*py + G[11]
//
// cull record (float4 x4 per face): bbox + sign-adjusted raw edge coeffs.

__global__ __launch_bounds__(256) void setup_faces(
    const float* __restrict__ v, const float* __restrict__ campos,
    const float* __restrict__ camrot, const float* __restrict__ focal,
    const float* __restrict__ princpt, const int* __restrict__ vi,
    float* __restrict__ face, double* __restrict__ dface, float4* __restrict__ cull)
{
#pragma clang fp contract(off)
    int t = blockIdx.x * blockDim.x + threadIdx.x;
    if (t >= NN * FF) return;
    int n = t / FF, f = t % FF;
    const float* cr = camrot + n * 9;
    const float* cp = campos + n * 3;
    const float* fo = focal + n * 4;
    const float* pp = princpt + n * 2;
    float X[3], Y[3], Z[3];
    for (int k = 0; k < 3; ++k) {
        int vid = vi[f * 3 + k];
        const float* vp = v + ((size_t)n * VV + vid) * 3;
        float d0 = vp[0] - cp[0];
        float d1 = vp[1] - cp[1];
        float d2 = vp[2] - cp[2];
        float c0 = (mulr(cr[0], d0) + mulr(cr[1], d1)) + mulr(cr[2], d2);
        float c1 = (mulr(cr[3], d0) + mulr(cr[4], d1)) + mulr(cr[5], d2);
        float c2 = (mulr(cr[6], d0) + mulr(cr[7], d1)) + mulr(cr[8], d2);
        float u = c0 / c2;
        float w = c1 / c2;
        X[k] = (mulr(fo[0], u) + mulr(fo[1], w)) + pp[0];
        Y[k] = (mulr(fo[2], u) + mulr(fo[3], w)) + pp[1];
        Z[k] = c2;
    }
    float area = mulr(X[1] - X[0], Y[2] - Y[0]) - mulr(Y[1] - Y[0], X[2] - X[0]);
    bool ok = fabsf(area) > 1e-9f;
    float inv = ok ? (1.0f / area) : __builtin_nanf("");
    float e0x = X[2] - X[1], e0y = Y[2] - Y[1];
    float e1x = X[0] - X[2], e1y = Y[0] - Y[2];
    float e2x = X[1] - X[0], e2y = Y[1] - Y[0];
    // fp32 record for render (unchanged)
    float* fd = face + (size_t)t * 16;
    fd[0] = X[0]; fd[1] = Y[0]; fd[2] = X[1]; fd[3] = Y[1]; fd[4] = X[2]; fd[5] = Y[2];
    fd[6] = e0x; fd[7] = e0y;
    fd[8] = e1x; fd[9] = e1y;
    fd[10] = e2x; fd[11] = e2y;
    fd[12] = inv;
    fd[13] = Z[0]; fd[14] = Z[1]; fd[15] = Z[2];
    // f64 affine record for raster
    double invd = (double)inv;
    double e0xd = (double)e0x, e0yd = (double)e0y;
    double e1xd = (double)e1x, e1yd = (double)e1y;
    double e2xd = (double)e2x, e2yd = (double)e2y;
    double x0d = (double)X[0], y0d = (double)Y[0];
    double x1d = (double)X[1], y1d = (double)Y[1];
    double x2d = (double)X[2], y2d = (double)Y[2];
    double rz0 = 1.0 / (double)Z[0];
    double rz1 = 1.0 / (double)Z[1];
    double rz2 = 1.0 / (double)Z[2];
    double Gx0 = -e0yd * invd, Gy0 = e0xd * invd, Gc0 = (e0yd * x1d - e0xd * y1d) * invd;
    double Gx1 = -e1yd * invd, Gy1 = e1xd * invd, Gc1 = (e1yd * x2d - e1xd * y2d) * invd;
    double Gx2 = -e2yd * invd, Gy2 = e2xd * invd, Gc2 = (e2yd * x0d - e2xd * y0d) * invd;
    double Zx = Gx0 * rz0 + Gx1 * rz1 + Gx2 * rz2;
    double Zy = Gy0 * rz0 + Gy1 * rz1 + Gy2 * rz2;
    double Zc = Gc0 * rz0 + Gc1 * rz1 + Gc2 * rz2;
    double* dd = dface + (size_t)t * 16;
    dd[0] = Gx0; dd[1] = Gy0; dd[2] = Gc0;
    dd[3] = Gx1; dd[4] = Gy1; dd[5] = Gc1;
    dd[6] = Gx2; dd[7] = Gy2; dd[8] = Gc2;
    dd[9] = Zx; dd[10] = Zy; dd[11] = Zc;
    dd[12] = 0.0; dd[13] = 0.0; dd[14] = 0.0; dd[15] = 0.0;
    // cull record
    float s = (area > 0.0f) ? 1.0f : -1.0f;
    float A0 = -e0y * s, B0 = e0x * s;
    float C0 = s * (float)(e0yd * x1d - e0xd * y1d);
    float A1 = -e1y * s, B1 = e1x * s;
    float C1 = s * (float)(e1yd * x2d - e1xd * y2d);
    float A2 = -e2y * s, B2 = e2x * s;
    float C2 = s * (float)(e2yd * x0d - e2xd * y0d);
    if (!ok) { C0 = -3e30f; C1 = -3e30f; C2 = -3e30f; }
    float xmn = fminf(fminf(X[0], X[1]), X[2]);
    float xmx = fmaxf(fmaxf(X[0], X[1]), X[2]);
    float ymn = fminf(fminf(Y[0], Y[1]), Y[2]);
    float ymx = fmaxf(fmaxf(Y[0], Y[1]), Y[2]);
    float4* cu = cull + (size_t)t * 4;
    cu[0] = make_float4(xmn, ymn, xmx, ymx);
    cu[1] = make_float4(A0, B0, C0, A1);
    cu[2] = make_float4(B1, C1, A2, B2);
    cu[3] = make_float4(C2, 0.0f, 0.0f, 0.0f);
}

__device__ __forceinline__ bool edge_keep(float A, float B, float C,
                                          float xlo, float xhi, float ylo, float yhi) {
    float m = A * ((A > 0.0f) ? xhi : xlo) + B * ((B > 0.0f) ? yhi : ylo) + C;
    return m >= -1.0f;   // margin ~0.01 px; f32 eval error << margin
}

// 8x8 pixel tile; 256 threads = 4 waves; wave w takes candidates w, w+4, ...
__global__ __launch_bounds__(256) void raster(
    const double* __restrict__ dface, const float4* __restrict__ cull,
    int* __restrict__ ibuf)
{
#pragma clang fp contract(fast)
    __shared__ int s_cnt;
    __shared__ int s_list[FF];
    __shared__ double s_z[4 * 64];
    __shared__ int s_f[4 * 64];
    int n = blockIdx.z;
    int tx0 = blockIdx.x * 8, ty0 = blockIdx.y * 8;
    int tid = threadIdx.x;
    int lane = tid & 63;
    int wv = tid >> 6;
    if (tid == 0) s_cnt = 0;
    __syncthreads();
    float xlo = (float)tx0, xhi = (float)(tx0 + 8);
    float ylo = (float)ty0, yhi = (float)(ty0 + 8);
    for (int f = tid; f < FF; f += 256) {
        const float4* cu = cull + ((size_t)n * FF + f) * 4;
        float4 bb = cu[0];
        if (bb.x <= xhi && bb.z >= xlo && bb.y <= yhi && bb.w >= ylo) {
            float4 c1 = cu[1], c2 = cu[2], c3 = cu[3];
            if (edge_keep(c1.x, c1.y, c1.z, xlo, xhi, ylo, yhi) &&
                edge_keep(c1.w, c2.x, c2.y, xlo, xhi, ylo, yhi) &&
                edge_keep(c2.z, c2.w, c3.x, xlo, xhi, ylo, yhi)) {
                int p = atomicAdd(&s_cnt, 1);
                s_list[p] = f;
            }
        }
    }
    __syncthreads();
    int cnt = s_cnt;
    double px = (double)(tx0 + (lane & 7)) + 0.5;
    double py = (double)(ty0 + (lane >> 3)) + 0.5;
    double best = 0.0;
    int bf = -1;
    for (int i = wv; i < cnt; i += 4) {
        int fid = __builtin_amdgcn_readfirstlane(s_list[i]);
        const double* g = dface + ((size_t)n * FF + fid) * 16;  // wave-uniform → s_load
        double b0 = g[0] * px + (g[1] * py + g[2]);
        double b1 = g[3] * px + (g[4] * py + g[5]);
        double b2 = g[6] * px + (g[7] * py + g[8]);
        double zinv = g[9] * px + (g[10] * py + g[11]);
        if (b0 >= 0.0 && b1 >= 0.0 && b2 >= 0.0 && zinv > EPSD) {
            if (zinv > best || (zinv == best && fid < bf)) {
                best = zinv;
                bf = fid;
            }
        }
    }
    s_z[wv * 64 + lane] = best;
    s_f[wv * 64 + lane] = bf;
    __syncthreads();
    if (tid < 64) {
        for (int w = 1; w < 4; ++w) {
            double z = s_z[w * 64 + tid];
            int ff = s_f[w * 64 + tid];
            if (ff >= 0 && (bf < 0 || z > best || (z == best && ff < bf))) {
                best = z;
                bf = ff;
            }
        }
        int x = tx0 + (tid & 7), y = ty0 + (tid >> 3);
        ibuf[((size_t)n * HH + y) * WW + x] = bf;
    }
}

// render: UNCHANGED from rounds 4/5/6 (op-for-op).
__device__ __forceinline__ void bary3_f64(
    const float4 q0, const float4 q1, const float4 q2, const float4 q3,
    double px, double py, double& b0, double& b1, double& b2)
{
    double invd = (double)q3.x;
    b0 = ((double)q1.z * (py - (double)q0.w) - (double)q1.w * (px - (double)q0.z)) * invd;
    b1 = ((double)q2.x * (py - (double)q1.y) - (double)q2.y * (px - (double)q1.x)) * invd;
    b2 = ((double)q2.z * (py - (double)q0.y) - (double)q2.w * (px - (double)q0.x)) * invd;
}

__global__ __launch_bounds__(256) void render(
    const float* __restrict__ face, const int* __restrict__ ibuf,
    const float* __restrict__ tex, const float* __restrict__ vt,
    const int* __restrict__ vti, float* __restrict__ out)
{
    int t = blockIdx.x * blockDim.x + threadIdx.x;
    if (t >= NN * HH * WW) return;
    int n = t / (HH * WW);
    int p = t % (HH * WW);
    int y = p / WW, x = p % WW;
    int f = ibuf[t];
    size_t o0 = ((size_t)(n * 3 + 0) * HH + y) * WW + x;
    size_t o1 = ((size_t)(n * 3 + 1) * HH + y) * WW + x;
    size_t o2 = ((size_t)(n * 3 + 2) * HH + y) * WW + x;
    if (f < 0) {
        out[o0] = 0.0f; out[o1] = 0.0f; out[o2] = 0.0f;
        return;
    }
    const float4* fp = (const float4*)(face + ((size_t)n * FF + f) * 16);
    float4 q0 = fp[0], q1 = fp[1], q2 = fp[2], q3 = fp[3];
    double px = (double)x + 0.5, py = (double)y + 0.5;
    double b0, b1, b2;
    bary3_f64(q0, q1, q2, q3, px, py, b0, b1, b2);
    double w0 = b0 / (double)q3.y;
    double w1 = b1 / (double)q3.z;
    double w2 = b2 / (double)q3.w;
    double s = (w0 + w1) + w2;
    double zq = fmax(s, EPSD);
    double bar0 = w0 / zq, bar1 = w1 / zq, bar2 = w2 / zq;
    int i0 = vti[f * 3 + 0], i1 = vti[f * 3 + 1], i2 = vti[f * 3 + 2];
    double u0 = (double)(2.0f * vt[i0 * 2 + 0] - 1.0f), v0 = (double)(2.0f * vt[i0 * 2 + 1] - 1.0f);
    double u1 = (double)(2.0f * vt[i1 * 2 + 0] - 1.0f), v1 = (double)(2.0f * vt[i1 * 2 + 1] - 1.0f);
    double u2 = (double)(2.0f * vt[i2 * 2 + 0] - 1.0f), v2 = (double)(2.0f * vt[i2 * 2 + 1] - 1.0f);
    double gx = (u0 * bar0 + u1 * bar1) + u2 * bar2;
    double gy = (v0 * bar0 + v1 * bar1) + v2 * bar2;
    double ix = ((gx + 1.0) * (double)TW - 1.0) * 0.5;
    double iy = ((gy + 1.0) * (double)TH - 1.0) * 0.5;
    double fx0 = floor(ix), fy0 = floor(iy);
    double wx = ix - fx0, wy = iy - fy0;
    int x0 = min(max((int)fx0, 0), TW - 1);
    int x1 = min(max((int)fx0 + 1, 0), TW - 1);
    int y0 = min(max((int)fy0, 0), TH - 1);
    int y1 = min(max((int)fy0 + 1, 0), TH - 1);
    double omwx = 1.0 - wx, omwy = 1.0 - wy;
    #pragma unroll
    for (int c = 0; c < 3; ++c) {
        const float* tc = tex + ((size_t)n * 3 + c) * TH * TW;
        double g00 = (double)tc[(size_t)y0 * TW + x0];
        double g01 = (double)tc[(size_t)y0 * TW + x1];
        double g10 = (double)tc[(size_t)y1 * TW + x0];
        double g11 = (double)tc[(size_t)y1 * TW + x1];
        double val = (((g00 * omwx) * omwy + (g01 * wx) * omwy)
                      + (g10 * omwx) * wy) + (g11 * wx) * wy;
        size_t oo = (c == 0) ? o0 : ((c == 1) ? o1 : o2);
        out[oo] = (float)val;
    }
}

extern "C" void kernel_launch(void* const* d_in, const int* in_sizes, int n_in,
                              void* d_out, int out_size, void* d_ws, size_t ws_size,
                              hipStream_t stream) {
    const float* v = (const float*)d_in[0];
    const float* tex = (const float*)d_in[1];
    const float* campos = (const float*)d_in[2];
    const float* camrot = (const float*)d_in[3];
    const float* focal = (const float*)d_in[4];
    const float* princpt = (const float*)d_in[5];
    const float* vt = (const float*)d_in[6];
    const int* vi = (const int*)d_in[7];
    const int* vti = (const int*)d_in[8];
    float* out = (float*)d_out;

    char* ws = (char*)d_ws;
    double* dface = (double*)ws;                       // 524288 B
    float* face = (float*)(ws + 524288);               // +262144 B
    float4* cull = (float4*)(ws + 524288 + 262144);    // +262144 B
    int* ibuf = (int*)(ws + 524288 + 262144 + 262144); // +1179648 B

    setup_faces<<<dim3((NN * FF + 255) / 256), dim3(256), 0, stream>>>(
        v, campos, camrot, focal, princpt, vi, face, dface, cull);
    raster<<<dim3(WW / 8, HH / 8, NN), dim3(256), 0, stream>>>(dface, cull, ibuf);
    render<<<dim3((NN * HH * WW + 255) / 256), dim3(256), 0, stream>>>(
        face, ibuf, tex, vt, vti, out);
}